// Round 1
// baseline (126.203 us; speedup 1.0000x reference)
//
#include <hip/hip_runtime.h>
#include <math.h>

// Problem constants (from reference)
#define BATCH    512
#define BATCH4   128          // BATCH / 4
#define N_VARS   4096
#define H_ROWS   (2 * N_VARS + 2)   // 8194
#define N_OUT0   16384
#define N_OUT1   8192
#define N_OUT2   4096
#define N_OUT3   2048
#define EPS      1e-15f
#define LOG2F_C  0.6931471805599453f

// accurate log(1 - exp(x)) for x < 0
__device__ __forceinline__ float log1mexp_f(float x) {
    if (x > -LOG2F_C) {
        return logf(-expm1f(x));
    } else {
        return log1pf(-expf(x));
    }
}

__device__ __forceinline__ float lse2_f(float a, float b) {
    float m = fmaxf(a, b);
    float s = expf(a - m) + expf(b - m);
    return logf(s + EPS) + m;
}

// Build h (8194 x 512): row0=-inf, row1=0, row 2i+2 = x[i], row 2i+3 = log1mexp(x[i])
__global__ void encode_kernel(const float* __restrict__ x, float* __restrict__ h) {
    int idx = blockIdx.x * blockDim.x + threadIdx.x;   // N_VARS * BATCH4 threads
    int i = idx >> 7;
    int b = idx & 127;
    if (i >= N_VARS) return;
    const float4* x4 = (const float4*)x;
    float4* h4 = (float4*)h;
    float4 p = x4[i * BATCH4 + b];
    float4 n;
    n.x = log1mexp_f(p.x);
    n.y = log1mexp_f(p.y);
    n.z = log1mexp_f(p.z);
    n.w = log1mexp_f(p.w);
    h4[(2 * i + 2) * BATCH4 + b] = p;
    h4[(2 * i + 3) * BATCH4 + b] = n;
    if (i == 0) {
        float4 ninf = make_float4(-INFINITY, -INFINITY, -INFINITY, -INFINITY);
        float4 zero = make_float4(0.f, 0.f, 0.f, 0.f);
        h4[0 * BATCH4 + b] = ninf;
        h4[1 * BATCH4 + b] = zero;
    }
}

// product layer: out[o][b] = sum_j in[ptrs[o*FANIN+j]][b]
template<int FANIN, int NOUT>
__global__ void product_kernel(const float* __restrict__ in,
                               const int* __restrict__ ptrs,
                               float* __restrict__ out) {
    int idx = blockIdx.x * blockDim.x + threadIdx.x;   // NOUT * BATCH4 threads
    int o = idx >> 7;
    int b = idx & 127;
    if (o >= NOUT) return;
    const float4* in4 = (const float4*)in;
    float4 acc = make_float4(0.f, 0.f, 0.f, 0.f);
#pragma unroll
    for (int j = 0; j < FANIN; ++j) {
        int p = ptrs[o * FANIN + j];
        float4 v = in4[p * BATCH4 + b];
        acc.x += v.x; acc.y += v.y; acc.z += v.z; acc.w += v.w;
    }
    ((float4*)out)[o * BATCH4 + b] = acc;
}

// sum (logsumexp) layer, fanin 2
template<int NOUT>
__global__ void sum2_kernel(const float* __restrict__ in,
                            const int* __restrict__ ptrs,
                            float* __restrict__ out) {
    int idx = blockIdx.x * blockDim.x + threadIdx.x;   // NOUT * BATCH4 threads
    int o = idx >> 7;
    int b = idx & 127;
    if (o >= NOUT) return;
    const float4* in4 = (const float4*)in;
    int p0 = ptrs[2 * o];
    int p1 = ptrs[2 * o + 1];
    float4 g0 = in4[p0 * BATCH4 + b];
    float4 g1 = in4[p1 * BATCH4 + b];
    float4 r;
    r.x = lse2_f(g0.x, g1.x);
    r.y = lse2_f(g0.y, g1.y);
    r.z = lse2_f(g0.z, g1.z);
    r.w = lse2_f(g0.w, g1.w);
    ((float4*)out)[o * BATCH4 + b] = r;
}

extern "C" void kernel_launch(void* const* d_in, const int* in_sizes, int n_in,
                              void* d_out, int out_size, void* d_ws, size_t ws_size,
                              hipStream_t stream) {
    const float* x     = (const float*)d_in[0];
    const int*   ptrs0 = (const int*)d_in[1];
    const int*   ptrs1 = (const int*)d_in[3];
    const int*   ptrs2 = (const int*)d_in[5];
    const int*   ptrs3 = (const int*)d_in[7];

    float* ws   = (float*)d_ws;
    float* h    = ws;                               // 8194*512 floats
    float* out0 = h + (size_t)H_ROWS * BATCH;       // 16384*512 floats
    float* out1 = h;                                // reuse h region (8194*512 >= 8192*512)
    float* out2 = out0 + (size_t)N_OUT0 * BATCH;    // 4096*512 floats
    float* out3 = (float*)d_out;                    // 2048*512 floats

    const int TPB = 256;

    // encode: N_VARS * 128 threads
    encode_kernel<<<(N_VARS * BATCH4) / TPB, TPB, 0, stream>>>(x, h);

    // layer 0: product fanin 4 -> out0
    product_kernel<4, N_OUT0><<<(N_OUT0 * BATCH4) / TPB, TPB, 0, stream>>>(h, ptrs0, out0);

    // layer 1: sum fanin 2 -> out1
    sum2_kernel<N_OUT1><<<(N_OUT1 * BATCH4) / TPB, TPB, 0, stream>>>(out0, ptrs1, out1);

    // layer 2: product fanin 4 -> out2
    product_kernel<4, N_OUT2><<<(N_OUT2 * BATCH4) / TPB, TPB, 0, stream>>>(out1, ptrs2, out2);

    // layer 3: sum fanin 2 -> d_out
    sum2_kernel<N_OUT3><<<(N_OUT3 * BATCH4) / TPB, TPB, 0, stream>>>(out2, ptrs3, out3);
}

// Round 2
// 125.936 us; speedup vs baseline: 1.0021x; 1.0021x over previous
//
#include <hip/hip_runtime.h>
#include <math.h>

// Problem constants (from reference)
#define BATCH    512
#define N_VARS   4096
#define H_ROWS   (2 * N_VARS + 2)   // 8194
#define N_OUT0   16384
#define N_OUT1   8192
#define N_OUT2   4096
#define N_OUT3   2048
#define EPS      1e-15f
#define LOG2F_C  0.6931471805599453f
#define TPB      512

// accurate log(1 - exp(x)) for x < 0
__device__ __forceinline__ float log1mexp_f(float x) {
    if (x > -LOG2F_C) {
        return logf(-expm1f(x));
    } else {
        return log1pf(-expf(x));
    }
}

__device__ __forceinline__ float lse2_f(float a, float b) {
    float m = fmaxf(a, b);
    float s = expf(a - m) + expf(b - m);
    return logf(s + EPS) + m;
}

// One workgroup per batch column. Entire 4-layer network fused; intermediates
// live in a single 8194-float LDS buffer (h, then overwritten by out1).
//   Phase A: encode x[:,b] -> buf (h layout: row0=-inf, row1=0, 2i+2=pos, 2i+3=neg)
//   Phase B: out1[o] = lse2(sum4(h[p0[p1a]]), sum4(h[p0[p1b]])) -> regs -> buf
//   Phase C: out3[o] = lse2(sum4(out1[p2[p3a]]), sum4(out1[p2[p3b]])) -> global
__global__ void __launch_bounds__(TPB, 4)
fused_spn_kernel(const float* __restrict__ x,
                 const int* __restrict__ p0,
                 const int* __restrict__ p1,
                 const int* __restrict__ p2,
                 const int* __restrict__ p3,
                 float* __restrict__ out) {
    __shared__ float buf[H_ROWS];
    const int b = blockIdx.x;    // batch column
    const int t = threadIdx.x;

    // ---- Phase A: encode ----
    if (t == 0) { buf[0] = -INFINITY; buf[1] = 0.f; }
#pragma unroll
    for (int k = 0; k < N_VARS / TPB; ++k) {
        int i = t + k * TPB;
        float p = x[(size_t)i * BATCH + b];
        buf[2 * i + 2] = p;
        buf[2 * i + 3] = log1mexp_f(p);
    }
    __syncthreads();

    // ---- Phase B: product(fanin4) + logsumexp(fanin2) -> out1 (regs) ----
    float r1[N_OUT1 / TPB];   // 16 per thread
#pragma unroll
    for (int k = 0; k < N_OUT1 / TPB; ++k) {
        int o = t + k * TPB;
        int2 pp = ((const int2*)p1)[o];
        int4 qa = ((const int4*)p0)[pp.x];
        int4 qb = ((const int4*)p0)[pp.y];
        float ga = buf[qa.x] + buf[qa.y] + buf[qa.z] + buf[qa.w];
        float gb = buf[qb.x] + buf[qb.y] + buf[qb.z] + buf[qb.w];
        r1[k] = lse2_f(ga, gb);
    }
    __syncthreads();   // everyone done reading h
#pragma unroll
    for (int k = 0; k < N_OUT1 / TPB; ++k) {
        buf[t + k * TPB] = r1[k];
    }
    __syncthreads();   // out1 visible

    // ---- Phase C: product(fanin4) + logsumexp(fanin2) -> d_out ----
#pragma unroll
    for (int k = 0; k < N_OUT3 / TPB; ++k) {
        int o = t + k * TPB;
        int2 pp = ((const int2*)p3)[o];
        int4 qa = ((const int4*)p2)[pp.x];
        int4 qb = ((const int4*)p2)[pp.y];
        float ga = buf[qa.x] + buf[qa.y] + buf[qa.z] + buf[qa.w];
        float gb = buf[qb.x] + buf[qb.y] + buf[qb.z] + buf[qb.w];
        out[(size_t)o * BATCH + b] = lse2_f(ga, gb);
    }
}

extern "C" void kernel_launch(void* const* d_in, const int* in_sizes, int n_in,
                              void* d_out, int out_size, void* d_ws, size_t ws_size,
                              hipStream_t stream) {
    const float* x     = (const float*)d_in[0];
    const int*   ptrs0 = (const int*)d_in[1];
    const int*   ptrs1 = (const int*)d_in[3];
    const int*   ptrs2 = (const int*)d_in[5];
    const int*   ptrs3 = (const int*)d_in[7];
    float* out = (float*)d_out;

    fused_spn_kernel<<<BATCH, TPB, 0, stream>>>(x, ptrs0, ptrs1, ptrs2, ptrs3, out);
}

// Round 3
// 119.240 us; speedup vs baseline: 1.0584x; 1.0562x over previous
//
#include <hip/hip_runtime.h>
#include <math.h>

// Problem constants (from reference)
#define BATCH    512
#define N_VARS   4096
#define H_ROWS   (2 * N_VARS + 2)   // 8194
#define N_OUT1   8192
#define N_OUT3   2048
#define TPB      1024

// Fast native-transcendental variants. Accuracy budget: threshold 0.38,
// exact-math absmax was 0.0625; these add <~1e-3.
__device__ __forceinline__ float log1mexp_fast(float x) {
    // x in (-9.22, -1e-4); 1-exp(x) in (1e-4, 1). Cancellation near 0 gives
    // abs err <= ~6e-4 in the log — fine at 0.38 threshold.
    return __logf(1.0f - __expf(x));
}

__device__ __forceinline__ float lse2_fast(float a, float b) {
    float m = fmaxf(a, b);
    float d = fabsf(a - b);
    return m + __logf(1.0f + __expf(-d));   // eps=1e-15 vanishes vs s>=1 in fp32
}

// 32x32 tiled transpose: in[R][C] -> out[C][R]. block (32,8), grid (C/32, R/32).
#define TDIM 32
__global__ void transpose_kernel(const float* __restrict__ in,
                                 float* __restrict__ out, int R, int C) {
    __shared__ float tile[TDIM][TDIM + 1];
    int cb = blockIdx.x * TDIM;
    int rb = blockIdx.y * TDIM;
    int tx = threadIdx.x, ty = threadIdx.y;
#pragma unroll
    for (int j = 0; j < TDIM; j += 8)
        tile[ty + j][tx] = in[(size_t)(rb + ty + j) * C + cb + tx];
    __syncthreads();
#pragma unroll
    for (int j = 0; j < TDIM; j += 8)
        out[(size_t)(cb + ty + j) * R + rb + tx] = tile[tx][ty + j];
}

// One workgroup (1024 thr = 16 waves) per batch column; 2 blocks/CU -> 100%
// occupancy cap. Whole 4-layer network fused; intermediates in one 8194-float
// LDS buffer. Reads xT (coalesced), writes outT (coalesced).
__global__ void __launch_bounds__(TPB, 8)
fused_spn_kernel(const float* __restrict__ xT,
                 const int* __restrict__ p0,
                 const int* __restrict__ p1,
                 const int* __restrict__ p2,
                 const int* __restrict__ p3,
                 float* __restrict__ outT) {
    __shared__ float buf[H_ROWS];
    const int b = blockIdx.x;
    const int t = threadIdx.x;

    // ---- Phase A: encode. float4 coalesced load of xT row b. ----
    if (t == 0) { buf[0] = -INFINITY; buf[1] = 0.f; }
    {
        float4 p = ((const float4*)(xT + (size_t)b * N_VARS))[t];   // vars 4t..4t+3
        int base = 8 * t + 2;
        buf[base + 0] = p.x;  buf[base + 1] = log1mexp_fast(p.x);
        buf[base + 2] = p.y;  buf[base + 3] = log1mexp_fast(p.y);
        buf[base + 4] = p.z;  buf[base + 5] = log1mexp_fast(p.z);
        buf[base + 6] = p.w;  buf[base + 7] = log1mexp_fast(p.w);
    }
    __syncthreads();

    // ---- Phase B: product(4) + lse(2) -> out1 in regs, then back into buf ----
    float r1[N_OUT1 / TPB];   // 8 per thread
#pragma unroll
    for (int k = 0; k < N_OUT1 / TPB; ++k) {
        int o = t + k * TPB;
        int2 pp = ((const int2*)p1)[o];
        int4 qa = ((const int4*)p0)[pp.x];
        int4 qb = ((const int4*)p0)[pp.y];
        float ga = buf[qa.x] + buf[qa.y] + buf[qa.z] + buf[qa.w];
        float gb = buf[qb.x] + buf[qb.y] + buf[qb.z] + buf[qb.w];
        r1[k] = lse2_fast(ga, gb);
    }
    __syncthreads();
#pragma unroll
    for (int k = 0; k < N_OUT1 / TPB; ++k)
        buf[t + k * TPB] = r1[k];
    __syncthreads();

    // ---- Phase C: product(4) + lse(2) -> outT (coalesced) ----
#pragma unroll
    for (int k = 0; k < N_OUT3 / TPB; ++k) {
        int o = t + k * TPB;
        int2 pp = ((const int2*)p3)[o];
        int4 qa = ((const int4*)p2)[pp.x];
        int4 qb = ((const int4*)p2)[pp.y];
        float ga = buf[qa.x] + buf[qa.y] + buf[qa.z] + buf[qa.w];
        float gb = buf[qb.x] + buf[qb.y] + buf[qb.z] + buf[qb.w];
        outT[(size_t)b * N_OUT3 + o] = lse2_fast(ga, gb);
    }
}

extern "C" void kernel_launch(void* const* d_in, const int* in_sizes, int n_in,
                              void* d_out, int out_size, void* d_ws, size_t ws_size,
                              hipStream_t stream) {
    const float* x     = (const float*)d_in[0];
    const int*   ptrs0 = (const int*)d_in[1];
    const int*   ptrs1 = (const int*)d_in[3];
    const int*   ptrs2 = (const int*)d_in[5];
    const int*   ptrs3 = (const int*)d_in[7];
    float* out = (float*)d_out;

    float* xT   = (float*)d_ws;                       // 4096*512 floats (8 MB)
    float* outT = xT + (size_t)N_VARS * BATCH;        // 2048*512 floats (4 MB)

    // x [4096][512] -> xT [512][4096]
    transpose_kernel<<<dim3(BATCH / TDIM, N_VARS / TDIM), dim3(32, 8), 0, stream>>>(
        x, xT, N_VARS, BATCH);

    fused_spn_kernel<<<BATCH, TPB, 0, stream>>>(xT, ptrs0, ptrs1, ptrs2, ptrs3, outT);

    // outT [512][2048] -> out [2048][512]
    transpose_kernel<<<dim3(N_OUT3 / TDIM, BATCH / TDIM), dim3(32, 8), 0, stream>>>(
        outT, out, BATCH, N_OUT3);
}

// Round 4
// 95.856 us; speedup vs baseline: 1.3166x; 1.2439x over previous
//
#include <hip/hip_runtime.h>
#include <math.h>

// Problem constants (from reference)
#define BATCH    512
#define N_VARS   4096
#define H_ROWS   (2 * N_VARS + 2)   // 8194
#define N_OUT1   8192
#define N_OUT3   2048
#define TPB      1024

// Fast native-transcendental variants. Accuracy budget: threshold 0.38,
// exact-math absmax was 0.0625; these add <~1e-3.
__device__ __forceinline__ float log1mexp_fast(float x) {
    return __logf(1.0f - __expf(x));
}

__device__ __forceinline__ float lse2_fast(float a, float b) {
    float m = fmaxf(a, b);
    float d = fabsf(a - b);
    return m + __logf(1.0f + __expf(-d));
}

// Fuse the two-level gather (sum-layer ptrs -> product-layer ptrs) into one
// index table: tab[2*o] and tab[2*o+1] hold the 8 source-row indices feeding
// sum-output o. Ptrs are batch-invariant, so this is done once per launch.
__global__ void build_tab_kernel(const int* __restrict__ p_prod,
                                 const int* __restrict__ p_sum,
                                 int4* __restrict__ tab, int n_out) {
    int o = blockIdx.x * blockDim.x + threadIdx.x;
    if (o >= n_out) return;
    int2 pp = ((const int2*)p_sum)[o];
    tab[2 * o]     = ((const int4*)p_prod)[pp.x];
    tab[2 * o + 1] = ((const int4*)p_prod)[pp.y];
}

// 32x32 tiled transpose: in[R][C] -> out[C][R]. block (32,8), grid (C/32, R/32).
#define TDIM 32
__global__ void transpose_kernel(const float* __restrict__ in,
                                 float* __restrict__ out, int R, int C) {
    __shared__ float tile[TDIM][TDIM + 1];
    int cb = blockIdx.x * TDIM;
    int rb = blockIdx.y * TDIM;
    int tx = threadIdx.x, ty = threadIdx.y;
#pragma unroll
    for (int j = 0; j < TDIM; j += 8)
        tile[ty + j][tx] = in[(size_t)(rb + ty + j) * C + cb + tx];
    __syncthreads();
#pragma unroll
    for (int j = 0; j < TDIM; j += 8)
        out[(size_t)(cb + ty + j) * R + rb + tx] = tile[tx][ty + j];
}

// One workgroup (1024 thr = 16 waves) per batch column. Whole 4-layer network
// fused; intermediates in one 8194-float LDS buffer. Index tables make every
// global-load address a pure function of threadIdx (max MLP, no ptr chains).
__global__ void __launch_bounds__(TPB, 8)
fused_spn_kernel(const float* __restrict__ xT,
                 const int4* __restrict__ tabB,
                 const int4* __restrict__ tabC,
                 float* __restrict__ outT) {
    __shared__ float buf[H_ROWS];
    const int b = blockIdx.x;
    const int t = threadIdx.x;

    // ---- Phase A: encode. float4 coalesced load of xT row b. ----
    if (t == 0) { buf[0] = -INFINITY; buf[1] = 0.f; }
    {
        float4 p = ((const float4*)(xT + (size_t)b * N_VARS))[t];
        int base = 8 * t + 2;
        buf[base + 0] = p.x;  buf[base + 1] = log1mexp_fast(p.x);
        buf[base + 2] = p.y;  buf[base + 3] = log1mexp_fast(p.y);
        buf[base + 4] = p.z;  buf[base + 5] = log1mexp_fast(p.z);
        buf[base + 6] = p.w;  buf[base + 7] = log1mexp_fast(p.w);
    }
    __syncthreads();

    // ---- Phase B: product(4)+lse(2) -> out1 regs, chunked 4-wide so the
    //      index loads for 4 outputs are all in flight before the gathers. ----
    float r1[N_OUT1 / TPB];   // 8 per thread
#pragma unroll
    for (int c = 0; c < N_OUT1 / TPB; c += 4) {
        int4 qa[4], qb[4];
#pragma unroll
        for (int k = 0; k < 4; ++k) {
            int o = t + (c + k) * TPB;
            qa[k] = tabB[2 * o];
            qb[k] = tabB[2 * o + 1];
        }
#pragma unroll
        for (int k = 0; k < 4; ++k) {
            float ga = buf[qa[k].x] + buf[qa[k].y] + buf[qa[k].z] + buf[qa[k].w];
            float gb = buf[qb[k].x] + buf[qb[k].y] + buf[qb[k].z] + buf[qb[k].w];
            r1[c + k] = lse2_fast(ga, gb);
        }
    }
    __syncthreads();
#pragma unroll
    for (int k = 0; k < N_OUT1 / TPB; ++k)
        buf[t + k * TPB] = r1[k];
    __syncthreads();

    // ---- Phase C: product(4)+lse(2) -> outT (coalesced) ----
    {
        int4 qa[2], qb[2];
#pragma unroll
        for (int k = 0; k < 2; ++k) {
            int o = t + k * TPB;
            qa[k] = tabC[2 * o];
            qb[k] = tabC[2 * o + 1];
        }
#pragma unroll
        for (int k = 0; k < 2; ++k) {
            int o = t + k * TPB;
            float ga = buf[qa[k].x] + buf[qa[k].y] + buf[qa[k].z] + buf[qa[k].w];
            float gb = buf[qb[k].x] + buf[qb[k].y] + buf[qb[k].z] + buf[qb[k].w];
            outT[(size_t)b * N_OUT3 + o] = lse2_fast(ga, gb);
        }
    }
}

extern "C" void kernel_launch(void* const* d_in, const int* in_sizes, int n_in,
                              void* d_out, int out_size, void* d_ws, size_t ws_size,
                              hipStream_t stream) {
    const float* x     = (const float*)d_in[0];
    const int*   ptrs0 = (const int*)d_in[1];
    const int*   ptrs1 = (const int*)d_in[3];
    const int*   ptrs2 = (const int*)d_in[5];
    const int*   ptrs3 = (const int*)d_in[7];
    float* out = (float*)d_out;

    float* xT   = (float*)d_ws;                       // 4096*512 floats (8 MB)
    float* outT = xT + (size_t)N_VARS * BATCH;        // 2048*512 floats (4 MB)
    int4*  tabB = (int4*)(outT + (size_t)N_OUT3 * BATCH);  // 8192*2 int4 (256 KB)
    int4*  tabC = tabB + 2 * N_OUT1;                       // 2048*2 int4 (64 KB)

    // Precompute fused gather tables (ptrs are batch-invariant).
    build_tab_kernel<<<N_OUT1 / 256, 256, 0, stream>>>(ptrs0, ptrs1, tabB, N_OUT1);
    build_tab_kernel<<<N_OUT3 / 256, 256, 0, stream>>>(ptrs2, ptrs3, tabC, N_OUT3);

    // x [4096][512] -> xT [512][4096]
    transpose_kernel<<<dim3(BATCH / TDIM, N_VARS / TDIM), dim3(32, 8), 0, stream>>>(
        x, xT, N_VARS, BATCH);

    fused_spn_kernel<<<BATCH, TPB, 0, stream>>>(xT, tabB, tabC, outT);

    // outT [512][2048] -> out [2048][512]
    transpose_kernel<<<dim3(N_OUT3 / TDIM, BATCH / TDIM), dim3(32, 8), 0, stream>>>(
        outT, out, BATCH, N_OUT3);
}

// Round 5
// 91.740 us; speedup vs baseline: 1.3757x; 1.0449x over previous
//
#include <hip/hip_runtime.h>
#include <math.h>

// Problem constants (from reference)
#define BATCH    512
#define N_VARS   4096
#define H_ROWS   (2 * N_VARS + 2)   // 8194
#define N_OUT1   8192
#define N_OUT3   2048
#define TPB      1024
#define SMEM_BYTES (H_ROWS * sizeof(float2))   // 65552 B — needs dynamic LDS

// Fast native-transcendental variants. Accuracy budget: threshold 0.38,
// exact-math absmax was 0.0625; these add <~1e-3.
__device__ __forceinline__ float log1mexp_fast(float x) {
    return __logf(1.0f - __expf(x));
}

__device__ __forceinline__ float2 lse2_fast2(float2 a, float2 b) {
    float2 r;
    float mx = fmaxf(a.x, b.x), my = fmaxf(a.y, b.y);
    r.x = mx + __logf(1.0f + __expf(-fabsf(a.x - b.x)));
    r.y = my + __logf(1.0f + __expf(-fabsf(a.y - b.y)));
    return r;
}

// Fuse the two-level gather (sum ptrs -> product ptrs) into index tables for
// both sum layers in ONE kernel. tab[2*o], tab[2*o+1] = 8 source rows of o.
__global__ void build_tabs_kernel(const int* __restrict__ p0,
                                  const int* __restrict__ p1,
                                  const int* __restrict__ p2,
                                  const int* __restrict__ p3,
                                  int4* __restrict__ tabB,
                                  int4* __restrict__ tabC) {
    int o = blockIdx.x * blockDim.x + threadIdx.x;
    if (o < N_OUT1) {
        int2 pp = ((const int2*)p1)[o];
        tabB[2 * o]     = ((const int4*)p0)[pp.x];
        tabB[2 * o + 1] = ((const int4*)p0)[pp.y];
    } else {
        int oc = o - N_OUT1;   // N_OUT3 outputs
        int2 pp = ((const int2*)p3)[oc];
        tabC[2 * oc]     = ((const int4*)p2)[pp.x];
        tabC[2 * oc + 1] = ((const int4*)p2)[pp.y];
    }
}

// 32x32 tiled transpose: in[R][C] -> out[C][R]. block (32,8), grid (C/32, R/32).
#define TDIM 32
__global__ void transpose_kernel(const float* __restrict__ in,
                                 float* __restrict__ out, int R, int C) {
    __shared__ float tile[TDIM][TDIM + 1];
    int cb = blockIdx.x * TDIM;
    int rb = blockIdx.y * TDIM;
    int tx = threadIdx.x, ty = threadIdx.y;
#pragma unroll
    for (int j = 0; j < TDIM; j += 8)
        tile[ty + j][tx] = in[(size_t)(rb + ty + j) * C + cb + tx];
    __syncthreads();
#pragma unroll
    for (int j = 0; j < TDIM; j += 8)
        out[(size_t)(cb + ty + j) * R + rb + tx] = tile[tx][ty + j];
}

// TWO batch columns per workgroup: LDS buf is float2 (lane .x = col b0,
// .y = col b1), so every random gather is one ds_read_b64 serving 2 columns —
// half the LDS wave-ops per column vs the 1-col version. 65552 B dynamic LDS.
__global__ void __launch_bounds__(TPB, 4)
fused_spn_kernel(const float* __restrict__ xT,
                 const int4* __restrict__ tabB,
                 const int4* __restrict__ tabC,
                 float* __restrict__ outT) {
    extern __shared__ float2 buf[];   // H_ROWS entries
    const int b0 = 2 * blockIdx.x;
    const int b1 = b0 + 1;
    const int t = threadIdx.x;

    // ---- Phase A: encode both columns (coalesced float4 loads from xT) ----
    if (t == 0) {
        buf[0] = make_float2(-INFINITY, -INFINITY);
        buf[1] = make_float2(0.f, 0.f);
    }
    {
        float4 pa = ((const float4*)(xT + (size_t)b0 * N_VARS))[t];  // vars 4t..4t+3
        float4 pb = ((const float4*)(xT + (size_t)b1 * N_VARS))[t];
        int base = 8 * t + 2;
        buf[base + 0] = make_float2(pa.x, pb.x);
        buf[base + 1] = make_float2(log1mexp_fast(pa.x), log1mexp_fast(pb.x));
        buf[base + 2] = make_float2(pa.y, pb.y);
        buf[base + 3] = make_float2(log1mexp_fast(pa.y), log1mexp_fast(pb.y));
        buf[base + 4] = make_float2(pa.z, pb.z);
        buf[base + 5] = make_float2(log1mexp_fast(pa.z), log1mexp_fast(pb.z));
        buf[base + 6] = make_float2(pa.w, pb.w);
        buf[base + 7] = make_float2(log1mexp_fast(pa.w), log1mexp_fast(pb.w));
    }
    __syncthreads();

    // ---- Phase B: product(4)+lse(2) -> out1 regs, chunked 4-wide for MLP ----
    float2 r1[N_OUT1 / TPB];   // 8 per thread
#pragma unroll
    for (int c = 0; c < N_OUT1 / TPB; c += 4) {
        int4 qa[4], qb[4];
#pragma unroll
        for (int k = 0; k < 4; ++k) {
            int o = t + (c + k) * TPB;
            qa[k] = tabB[2 * o];
            qb[k] = tabB[2 * o + 1];
        }
#pragma unroll
        for (int k = 0; k < 4; ++k) {
            float2 va0 = buf[qa[k].x], va1 = buf[qa[k].y];
            float2 va2 = buf[qa[k].z], va3 = buf[qa[k].w];
            float2 vb0 = buf[qb[k].x], vb1 = buf[qb[k].y];
            float2 vb2 = buf[qb[k].z], vb3 = buf[qb[k].w];
            float2 ga = make_float2(va0.x + va1.x + va2.x + va3.x,
                                    va0.y + va1.y + va2.y + va3.y);
            float2 gb = make_float2(vb0.x + vb1.x + vb2.x + vb3.x,
                                    vb0.y + vb1.y + vb2.y + vb3.y);
            r1[c + k] = lse2_fast2(ga, gb);
        }
    }
    __syncthreads();
#pragma unroll
    for (int k = 0; k < N_OUT1 / TPB; ++k)
        buf[t + k * TPB] = r1[k];
    __syncthreads();

    // ---- Phase C: product(4)+lse(2) -> outT rows b0,b1 (coalesced) ----
    {
        int4 qa[2], qb[2];
#pragma unroll
        for (int k = 0; k < 2; ++k) {
            int o = t + k * TPB;
            qa[k] = tabC[2 * o];
            qb[k] = tabC[2 * o + 1];
        }
#pragma unroll
        for (int k = 0; k < 2; ++k) {
            int o = t + k * TPB;
            float2 va0 = buf[qa[k].x], va1 = buf[qa[k].y];
            float2 va2 = buf[qa[k].z], va3 = buf[qa[k].w];
            float2 vb0 = buf[qb[k].x], vb1 = buf[qb[k].y];
            float2 vb2 = buf[qb[k].z], vb3 = buf[qb[k].w];
            float2 ga = make_float2(va0.x + va1.x + va2.x + va3.x,
                                    va0.y + va1.y + va2.y + va3.y);
            float2 gb = make_float2(vb0.x + vb1.x + vb2.x + vb3.x,
                                    vb0.y + vb1.y + vb2.y + vb3.y);
            float2 r = lse2_fast2(ga, gb);
            outT[(size_t)b0 * N_OUT3 + o] = r.x;
            outT[(size_t)b1 * N_OUT3 + o] = r.y;
        }
    }
}

extern "C" void kernel_launch(void* const* d_in, const int* in_sizes, int n_in,
                              void* d_out, int out_size, void* d_ws, size_t ws_size,
                              hipStream_t stream) {
    const float* x     = (const float*)d_in[0];
    const int*   ptrs0 = (const int*)d_in[1];
    const int*   ptrs1 = (const int*)d_in[3];
    const int*   ptrs2 = (const int*)d_in[5];
    const int*   ptrs3 = (const int*)d_in[7];
    float* out = (float*)d_out;

    float* xT   = (float*)d_ws;                       // 4096*512 floats (8 MB)
    float* outT = xT + (size_t)N_VARS * BATCH;        // 2048*512 floats (4 MB)
    int4*  tabB = (int4*)(outT + (size_t)N_OUT3 * BATCH);  // 8192*2 int4 (256 KB)
    int4*  tabC = tabB + 2 * N_OUT1;                       // 2048*2 int4 (64 KB)

    // Allow >64 KB dynamic LDS for the fused kernel (gfx950: 160 KB/WG max).
    static bool attr_set = false;
    if (!attr_set) {
        hipFuncSetAttribute((const void*)fused_spn_kernel,
                            hipFuncAttributeMaxDynamicSharedMemorySize, SMEM_BYTES);
        attr_set = true;
    }

    // Precompute fused gather tables (ptrs are batch-invariant).
    build_tabs_kernel<<<(N_OUT1 + N_OUT3) / 256, 256, 0, stream>>>(
        ptrs0, ptrs1, ptrs2, ptrs3, tabB, tabC);

    // x [4096][512] -> xT [512][4096]
    transpose_kernel<<<dim3(BATCH / TDIM, N_VARS / TDIM), dim3(32, 8), 0, stream>>>(
        x, xT, N_VARS, BATCH);

    fused_spn_kernel<<<BATCH / 2, TPB, SMEM_BYTES, stream>>>(xT, tabB, tabC, outT);

    // outT [512][2048] -> out [2048][512]
    transpose_kernel<<<dim3(N_OUT3 / TDIM, BATCH / TDIM), dim3(32, 8), 0, stream>>>(
        outT, out, BATCH, N_OUT3);
}